// Round 17
// baseline (258.509 us; speedup 1.0000x reference)
//
#include <hip/hip_runtime.h>
#include <hip/hip_fp16.h>

// GCN 2-layer: x[N,128] @ W1[128,64] -> gcn_conv -> relu -> @ W2[64,40] -> gcn_conv -> relu
// N = 100000, E = 1600000 (derived from in_sizes at launch).
//
// R17: fuse gather64+gemm2 into one kernel. After the gather's relu, the g-row
// lives across the wave's 64 lanes (lane=feature); gemm2 for that row =
// 64x {__shfl broadcast (v_readlane, ~free) + LDS W2 read + fma} per lane
// c<40, hidden under other waves' gather latency. Deletes g1h (12.8MB RW),
// k_stage/k_gemm2 (7->5 launches), the R11-13 pipeline machinery; grow stays
// fp32 (one fewer rounding).
// R16: h2 rows padded to 64 halves (128B aligned) — gather40 one extent/edge.
// R15: single-pass ELL build inside gemmrank (atomic + fire-and-forget
// scatter). R14 (null): gathers at L3 request-rate floor; 16-deep kept.
// R12: liveness under pipelining — no hidden aliases (g1 gone now anyway).
// R10: rank atomics (66us fabric floor) hidden under gemm1, same-footprint
// role split. R9 (null): atomic = fixed fabric packet.
// R8: pre-scaled hs=invs*h. R7: fp16 gather operands.
// R3: gemm b-loop unroll capped at 2 (else 256-VGPR spill).

#define F0 128
#define F1 64
#define F2 40
#define H2S 64                 // h2 row stride (padded from 40)
#define ELLW 64
#define GEMM_BLKS 768          // gemmrank grid; 512 gemm + 256 rank
#define NRANK (GEMM_BLKS / 3)  // 256 rank-role blocks

// ---------------- zero int counts ----------------
__global__ void k_zero(int* __restrict__ cnt, int n) {
    const int i = blockIdx.x * blockDim.x + threadIdx.x;
    if (i < n) cnt[i] = 0;
}

// ---------------- fused: gemm1 (2 of 3 blocks) + rank/ELL-fill (1 of 3) ----------------
__global__ __launch_bounds__(256) void k_gemmrank(const float* __restrict__ x,
                                                  const float* __restrict__ W,
                                                  __half* __restrict__ h,
                                                  const int* __restrict__ ei,
                                                  int* __restrict__ cnt,
                                                  int* __restrict__ ell,
                                                  int n, int E) {
    __shared__ float Wl[F0 * F1];   // 32 KB
    __shared__ float xs[32 * F0];   // 16 KB
    const int bid = blockIdx.x;
    const int tid = threadIdx.x;

    if ((bid % 3) == 2) {
        // ---- rank+fill role: 256 blocks, grid-stride over edges ----
        const int rb = bid / 3;
        const int stride = NRANK * 256;
#pragma unroll 4
        for (int e = rb * 256 + tid; e < E; e += stride) {
            const int s = ei[e];
            const int d = ei[E + e];
            const int r = atomicAdd(&cnt[d], 1);
            if (r < ELLW) ell[(long long)d * ELLW + r] = s;
        }
        return;
    }

    // ---- gemm role ----
    const int gid = bid - bid / 3;
    const int c = tid & 63;
    const int rq = tid >> 6;

    {
        float4* Wl4 = (float4*)Wl;
        const float4* Wg4 = (const float4*)W;
#pragma unroll
        for (int j = 0; j < (F0 * F1 / 4) / 256; ++j)
            Wl4[j * 256 + tid] = Wg4[j * 256 + tid];
    }
    __syncthreads();

    const int NG = GEMM_BLKS - NRANK;           // 512
    const int ntiles = (n + 31) >> 5;
    for (int tile = gid; tile < ntiles; tile += NG) {
        float4* xs4w = (float4*)xs;
#pragma unroll
        for (int j = 0; j < 4; ++j) {
            int fi = j * 256 + tid;
            int row = fi >> 5;
            int rg = tile * 32 + row;
            if (rg > n - 1) rg = n - 1;
            const float4* xrow = (const float4*)(x + (long long)rg * F0);
            xs4w[fi] = xrow[fi & 31];
        }
        __syncthreads();

        float acc[8] = {0.f,0.f,0.f,0.f,0.f,0.f,0.f,0.f};
#pragma unroll 2
        for (int b = 0; b < 32; ++b) {
            const float w0 = Wl[(4 * b + 0) * F1 + c];
            const float w1 = Wl[(4 * b + 1) * F1 + c];
            const float w2 = Wl[(4 * b + 2) * F1 + c];
            const float w3 = Wl[(4 * b + 3) * F1 + c];
#pragma unroll
            for (int i = 0; i < 8; ++i) {
                float4 xv = ((const float4*)xs)[(rq * 8 + i) * 32 + b];
                acc[i] = fmaf(xv.w, w3, fmaf(xv.z, w2, fmaf(xv.y, w1, fmaf(xv.x, w0, acc[i]))));
            }
        }

#pragma unroll
        for (int i = 0; i < 8; ++i) {
            int rg = tile * 32 + rq * 8 + i;
            if (rg < n) h[(long long)rg * F1 + c] = __float2half(acc[i]);
        }
        __syncthreads();
    }
}

// ---------------- fused: invs = rsqrt(cnt+1) (role A) | scale h1h rows (role B) ----------------
__global__ void k_rsqrt_scale(const int* __restrict__ cnt, float* __restrict__ invs,
                              __half* __restrict__ h, int n, int gINV) {
    const int bid = blockIdx.x;
    const int tid = threadIdx.x;
    if (bid < gINV) {
        const int i = bid * 256 + tid;
        if (i < n) invs[i] = rsqrtf((float)(cnt[i] + 1));
    } else {
        const int fb = bid - gINV;
        const long long total4 = (long long)n * F1 / 4;   // n*16 half4 groups
        long long i4 = (long long)fb * 256 + tid;
        const long long stride = (long long)2048 * 256;
        for (; i4 < total4; i4 += stride) {
            const int r = (int)(i4 >> 4);
            const float iv = rsqrtf((float)(cnt[r] + 1));
            __half2* hp = (__half2*)h + i4 * 2;
            __half2 a = hp[0], b = hp[1];
            float2 af = __half22float2(a), bf = __half22float2(b);
            af.x *= iv; af.y *= iv; bf.x *= iv; bf.y *= iv;
            hp[0] = __float22half2_rn(af);
            hp[1] = __float22half2_rn(bf);
        }
    }
}

// ---------------- fused gather64 + gemm2 (ELL): one wave per row ----------------
// grow[lane] = relu(iv*(sum_s hs[s][lane] + hs[w][lane]))   (fp32, in-register)
// h2[w][c]   = iv * sum_k grow[k] * W2[k][c]   via __shfl broadcast of grow.
__global__ __launch_bounds__(256) void k_gathergemm2(const int* __restrict__ cnt,
                                                     const int* __restrict__ ell,
                                                     const float* __restrict__ invs,
                                                     const __half* __restrict__ h1,
                                                     const float* __restrict__ W2,
                                                     __half* __restrict__ h2, int n) {
    __shared__ float Wl[F1 * F2];   // 10.24 KB
    const int tid = threadIdx.x;
    for (int i = tid; i < F1 * F2; i += 256) Wl[i] = W2[i];
    __syncthreads();

    const int wv = tid >> 6;
    const int lane = tid & 63;
    const int cc = (lane < F2) ? lane : (F2 - 1);   // clamped col for idle lanes
    const int waves = gridDim.x * 4;

    for (int w = blockIdx.x * 4 + wv; w < n; w += waves) {
        const int deg = min(cnt[w], ELLW);
        const int* row = ell + (long long)w * ELLW;
        float acc0 = 0.f, acc1 = 0.f, acc2 = 0.f, acc3 = 0.f;
        int k = 0;
        for (; k + 16 <= deg; k += 16) {
            int ss[16];
#pragma unroll
            for (int j = 0; j < 16; ++j) ss[j] = row[k + j];
            float vv[16];
#pragma unroll
            for (int j = 0; j < 16; ++j)
                vv[j] = __half2float(h1[(long long)ss[j] * F1 + lane]);
            acc0 += ((vv[0] + vv[4]) + (vv[8]  + vv[12]));
            acc1 += ((vv[1] + vv[5]) + (vv[9]  + vv[13]));
            acc2 += ((vv[2] + vv[6]) + (vv[10] + vv[14]));
            acc3 += ((vv[3] + vv[7]) + (vv[11] + vv[15]));
        }
        for (; k + 8 <= deg; k += 8) {
            const int s0 = row[k+0], s1 = row[k+1], s2 = row[k+2], s3 = row[k+3];
            const int s4 = row[k+4], s5 = row[k+5], s6 = row[k+6], s7 = row[k+7];
            const float v0 = __half2float(h1[(long long)s0 * F1 + lane]);
            const float v1 = __half2float(h1[(long long)s1 * F1 + lane]);
            const float v2 = __half2float(h1[(long long)s2 * F1 + lane]);
            const float v3 = __half2float(h1[(long long)s3 * F1 + lane]);
            const float v4 = __half2float(h1[(long long)s4 * F1 + lane]);
            const float v5 = __half2float(h1[(long long)s5 * F1 + lane]);
            const float v6 = __half2float(h1[(long long)s6 * F1 + lane]);
            const float v7 = __half2float(h1[(long long)s7 * F1 + lane]);
            acc0 += v0 + v4; acc1 += v1 + v5; acc2 += v2 + v6; acc3 += v3 + v7;
        }
        for (; k + 2 <= deg; k += 2) {
            const int s0 = row[k], s1 = row[k+1];
            acc0 += __half2float(h1[(long long)s0 * F1 + lane]);
            acc1 += __half2float(h1[(long long)s1 * F1 + lane]);
        }
        if (k < deg) {
            acc0 += __half2float(h1[(long long)row[k] * F1 + lane]);
        }
        const float iv = invs[w];
        const float self = __half2float(h1[(long long)w * F1 + lane]);
        const float grow = fmaxf(iv * (((acc0 + acc1) + (acc2 + acc3)) + self), 0.f);

        // gemm2 for this row: o[c] = sum_k grow[k] * W2[k][c]
        float o = 0.f;
#pragma unroll 4
        for (int kk = 0; kk < F1; ++kk) {
            const float bc = __shfl(grow, kk, 64);
            o = fmaf(bc, Wl[kk * F2 + cc], o);
        }
        if (lane < F2)
            h2[(long long)w * H2S + lane] = __float2half(o * iv);
    }
}

// ---------------- gather L2 (F=40, ELL), h2 stride H2S, writes fp32 out ----------------
__global__ __launch_bounds__(256) void k_gather40(const int* __restrict__ cnt,
                                                  const int* __restrict__ ell,
                                                  const float* __restrict__ invs,
                                                  const __half* __restrict__ h,
                                                  float* __restrict__ g, int n) {
    const int w = (blockIdx.x * blockDim.x + threadIdx.x) >> 6;
    const int lane = threadIdx.x & 63;
    if (w >= n) return;
    const int deg = min(cnt[w], ELLW);
    const int* row = ell + (long long)w * ELLW;
    float acc0 = 0.f, acc1 = 0.f, acc2 = 0.f, acc3 = 0.f;
    int k = 0;
    if (lane < F2) {
        for (; k + 16 <= deg; k += 16) {
            int ss[16];
#pragma unroll
            for (int j = 0; j < 16; ++j) ss[j] = row[k + j];
            float vv[16];
#pragma unroll
            for (int j = 0; j < 16; ++j)
                vv[j] = __half2float(h[(long long)ss[j] * H2S + lane]);
            acc0 += ((vv[0] + vv[4]) + (vv[8]  + vv[12]));
            acc1 += ((vv[1] + vv[5]) + (vv[9]  + vv[13]));
            acc2 += ((vv[2] + vv[6]) + (vv[10] + vv[14]));
            acc3 += ((vv[3] + vv[7]) + (vv[11] + vv[15]));
        }
        for (; k + 8 <= deg; k += 8) {
            const int s0 = row[k+0], s1 = row[k+1], s2 = row[k+2], s3 = row[k+3];
            const int s4 = row[k+4], s5 = row[k+5], s6 = row[k+6], s7 = row[k+7];
            const float v0 = __half2float(h[(long long)s0 * H2S + lane]);
            const float v1 = __half2float(h[(long long)s1 * H2S + lane]);
            const float v2 = __half2float(h[(long long)s2 * H2S + lane]);
            const float v3 = __half2float(h[(long long)s3 * H2S + lane]);
            const float v4 = __half2float(h[(long long)s4 * H2S + lane]);
            const float v5 = __half2float(h[(long long)s5 * H2S + lane]);
            const float v6 = __half2float(h[(long long)s6 * H2S + lane]);
            const float v7 = __half2float(h[(long long)s7 * H2S + lane]);
            acc0 += v0 + v4; acc1 += v1 + v5; acc2 += v2 + v6; acc3 += v3 + v7;
        }
        for (; k + 2 <= deg; k += 2) {
            const int s0 = row[k], s1 = row[k+1];
            acc0 += __half2float(h[(long long)s0 * H2S + lane]);
            acc1 += __half2float(h[(long long)s1 * H2S + lane]);
        }
        if (k < deg) {
            acc0 += __half2float(h[(long long)row[k] * H2S + lane]);
        }
        const float iv = invs[w];
        const float self = __half2float(h[(long long)w * H2S + lane]);
        g[(long long)w * F2 + lane] = fmaxf(iv * (((acc0 + acc1) + (acc2 + acc3)) + self), 0.f);
    }
}

extern "C" void kernel_launch(void* const* d_in, const int* in_sizes, int n_in,
                              void* d_out, int out_size, void* d_ws, size_t ws_size,
                              hipStream_t stream) {
    const float* x  = (const float*)d_in[0];
    const int*   ei = (const int*)d_in[1];
    const float* W1 = (const float*)d_in[2];
    const float* W2 = (const float*)d_in[3];
    float* out = (float*)d_out;
    const int n = in_sizes[0] / F0;     // 100000
    const int E = in_sizes[1] / 2;      // 1600000

    // ws layout (~52MB): cnt[np] | invs[np] | ell[n*64] | h1h[n*64 half]
    //                    | h2h[n*H2S half]      (g1h eliminated — R17)
    const size_t np = ((size_t)n + 65) & ~(size_t)63;
    char* wsb = (char*)d_ws;
    int*    cnt  = (int*)wsb;
    float*  invs = (float*)(cnt + np);
    int*    ell  = (int*)(invs + np);                    // n*64 ints
    __half* h1h  = (__half*)(ell + (size_t)n * ELLW);    // n*64 halves
    __half* h2h  = h1h + (size_t)n * F1;                 // n*H2S halves

    const int gN = (n + 255) / 256;                 // 391
    const int gW = (int)(((long long)n * 64 + 255) / 256);  // gather40: 1 wave/node
    const int gGG = 2048;                           // gathergemm2: grid-stride, 8192 waves

    // L1: zero counters
    hipLaunchKernelGGL(k_zero, dim3(gN), dim3(256), 0, stream, cnt, n);
    // L2: gemm1 || rank+ELL-fill
    hipLaunchKernelGGL(k_gemmrank, dim3(GEMM_BLKS), dim3(256), 0, stream,
                       x, W1, h1h, ei, cnt, ell, n, E);
    // L3: invs = rsqrt(cnt+1) || scale h1h rows by rsqrt(cnt[r]+1)
    hipLaunchKernelGGL(k_rsqrt_scale, dim3(gN + 2048), dim3(256), 0, stream,
                       cnt, invs, h1h, n, gN);
    // L4: fused gather64 + gemm2 (full n)
    hipLaunchKernelGGL(k_gathergemm2, dim3(gGG), dim3(256), 0, stream,
                       cnt, ell, invs, h1h, W2, h2h, n);
    // L5: gather40 full
    hipLaunchKernelGGL(k_gather40, dim3(gW), dim3(256), 0, stream,
                       cnt, ell, invs, h2h, out, n);
}

// Round 18
// 222.510 us; speedup vs baseline: 1.1618x; 1.1618x over previous
//
#include <hip/hip_runtime.h>
#include <hip/hip_fp16.h>

// GCN 2-layer: x[N,128] @ W1[128,64] -> gcn_conv -> relu -> @ W2[64,40] -> gcn_conv -> relu
// N = 100000, E = 1600000 (derived from in_sizes at launch).
//
// R18: REVERT of R17 (fused gather64+gemm2 regressed 223->258us: the serial
// 64-step __shfl dot-product between gather bursts throttled the request
// stream — FETCH throughput 2TB/s -> 765GB/s. Lesson: don't put a serial
// epilogue on the critical wave of a request-rate-bound loop).
// This is the R16 kernel: believed near-roofline.
// R16: h2 rows padded to 64 halves (128B aligned) — gather40 one extent/edge.
// R15: single-pass ELL build inside gemmrank (rank atomics + fire-and-forget
// scatter; deleted scan/fill ceremony, g1 fp16).
// R14 (null): gathers at L3 request-rate floor; 16-deep unroll kept.
// R13: only row-local g64/gm2 chaining (VALU||fabric overlaps; lat||lat sums).
// R12: h2h must NOT alias h1h (liveness extends under pipelining).
// R10: rank atomics (66us fabric floor) hidden under gemm1, same-footprint
// role split. R9 (null): atomic = fixed fabric packet; padding cnt useless.
// R8: pre-scaled hs=invs*h. R7: fp16 gather operands.
// R3: gemm b-loop unroll capped at 2 (else 256-VGPR spill).

#define F0 128
#define F1 64
#define F2 40
#define H2S 64                 // h2 row stride (padded from 40)
#define ELLW 64
#define GEMM_BLKS 768          // gemmrank grid; 512 gemm + 256 rank
#define NRANK (GEMM_BLKS / 3)  // 256 rank-role blocks
#define STG_GM 512             // gemm-role blocks inside k_stage

// ---------------- zero int counts ----------------
__global__ void k_zero(int* __restrict__ cnt, int n) {
    const int i = blockIdx.x * blockDim.x + threadIdx.x;
    if (i < n) cnt[i] = 0;
}

// ---------------- fused: gemm1 (2 of 3 blocks) + rank/ELL-fill (1 of 3) ----------------
__global__ __launch_bounds__(256) void k_gemmrank(const float* __restrict__ x,
                                                  const float* __restrict__ W,
                                                  __half* __restrict__ h,
                                                  const int* __restrict__ ei,
                                                  int* __restrict__ cnt,
                                                  int* __restrict__ ell,
                                                  int n, int E) {
    __shared__ float Wl[F0 * F1];   // 32 KB
    __shared__ float xs[32 * F0];   // 16 KB
    const int bid = blockIdx.x;
    const int tid = threadIdx.x;

    if ((bid % 3) == 2) {
        // ---- rank+fill role: 256 blocks, grid-stride over edges ----
        const int rb = bid / 3;
        const int stride = NRANK * 256;
#pragma unroll 4
        for (int e = rb * 256 + tid; e < E; e += stride) {
            const int s = ei[e];
            const int d = ei[E + e];
            const int r = atomicAdd(&cnt[d], 1);
            if (r < ELLW) ell[(long long)d * ELLW + r] = s;
        }
        return;
    }

    // ---- gemm role ----
    const int gid = bid - bid / 3;
    const int c = tid & 63;
    const int rq = tid >> 6;

    {
        float4* Wl4 = (float4*)Wl;
        const float4* Wg4 = (const float4*)W;
#pragma unroll
        for (int j = 0; j < (F0 * F1 / 4) / 256; ++j)
            Wl4[j * 256 + tid] = Wg4[j * 256 + tid];
    }
    __syncthreads();

    const int NG = GEMM_BLKS - NRANK;           // 512
    const int ntiles = (n + 31) >> 5;
    for (int tile = gid; tile < ntiles; tile += NG) {
        float4* xs4w = (float4*)xs;
#pragma unroll
        for (int j = 0; j < 4; ++j) {
            int fi = j * 256 + tid;
            int row = fi >> 5;
            int rg = tile * 32 + row;
            if (rg > n - 1) rg = n - 1;
            const float4* xrow = (const float4*)(x + (long long)rg * F0);
            xs4w[fi] = xrow[fi & 31];
        }
        __syncthreads();

        float acc[8] = {0.f,0.f,0.f,0.f,0.f,0.f,0.f,0.f};
#pragma unroll 2
        for (int b = 0; b < 32; ++b) {
            const float w0 = Wl[(4 * b + 0) * F1 + c];
            const float w1 = Wl[(4 * b + 1) * F1 + c];
            const float w2 = Wl[(4 * b + 2) * F1 + c];
            const float w3 = Wl[(4 * b + 3) * F1 + c];
#pragma unroll
            for (int i = 0; i < 8; ++i) {
                float4 xv = ((const float4*)xs)[(rq * 8 + i) * 32 + b];
                acc[i] = fmaf(xv.w, w3, fmaf(xv.z, w2, fmaf(xv.y, w1, fmaf(xv.x, w0, acc[i]))));
            }
        }

#pragma unroll
        for (int i = 0; i < 8; ++i) {
            int rg = tile * 32 + rq * 8 + i;
            if (rg < n) h[(long long)rg * F1 + c] = __float2half(acc[i]);
        }
        __syncthreads();
    }
}

// ---------------- fused: invs = rsqrt(cnt+1) (role A) | scale h1h rows (role B) ----------------
__global__ void k_rsqrt_scale(const int* __restrict__ cnt, float* __restrict__ invs,
                              __half* __restrict__ h, int n, int gINV) {
    const int bid = blockIdx.x;
    const int tid = threadIdx.x;
    if (bid < gINV) {
        const int i = bid * 256 + tid;
        if (i < n) invs[i] = rsqrtf((float)(cnt[i] + 1));
    } else {
        const int fb = bid - gINV;
        const long long total4 = (long long)n * F1 / 4;   // n*16 half4 groups
        long long i4 = (long long)fb * 256 + tid;
        const long long stride = (long long)2048 * 256;
        for (; i4 < total4; i4 += stride) {
            const int r = (int)(i4 >> 4);
            const float iv = rsqrtf((float)(cnt[r] + 1));
            __half2* hp = (__half2*)h + i4 * 2;
            __half2 a = hp[0], b = hp[1];
            float2 af = __half22float2(a), bf = __half22float2(b);
            af.x *= iv; af.y *= iv; bf.x *= iv; bf.y *= iv;
            hp[0] = __float22half2_rn(af);
            hp[1] = __float22half2_rn(bf);
        }
    }
}

// ================= shared role bodies =================

// gemm2 role: h2[r,:40](fp16, stride H2S) = invs[r]*(g[r,:64](fp16) @ W2), rows [lo,hi)
__device__ __forceinline__ void gemm2_body(const __half* __restrict__ g,
                                           const float* __restrict__ W,
                                           const float* __restrict__ invs,
                                           __half* __restrict__ h,
                                           int n, int lo, int hi,
                                           int relbid, int nblk, int tid) {
    __shared__ float Wl[F1 * F2];   // 10 KB
    __shared__ float xs[32 * F1];   // 8 KB
    const int c = tid & 63;
    const int rq = tid >> 6;

    for (int i = tid; i < F1 * F2; i += 256) Wl[i] = W[i];
    __syncthreads();

    const int t0 = lo >> 5;
    const int ntiles = (hi - lo + 31) >> 5;
    for (int ti = relbid; ti < ntiles; ti += nblk) {
        const int tile = t0 + ti;
        {   // stage 32 rows x 64 halves (4KB): 16B = 8 halves per thread
            const int row = tid >> 3;          // 0..31
            const int ch  = tid & 7;           // 0..7
            int rg = tile * 32 + row;
            if (rg > n - 1) rg = n - 1;
            const float4 raw = *(const float4*)(g + (long long)rg * F1 + ch * 8);
            const __half2* hp = (const __half2*)&raw;
            const float2 f0 = __half22float2(hp[0]);
            const float2 f1 = __half22float2(hp[1]);
            const float2 f2 = __half22float2(hp[2]);
            const float2 f3 = __half22float2(hp[3]);
            float4* dst = (float4*)&xs[row * F1 + ch * 8];
            dst[0] = make_float4(f0.x, f0.y, f1.x, f1.y);
            dst[1] = make_float4(f2.x, f2.y, f3.x, f3.y);
        }
        __syncthreads();

        if (c < F2) {
            float acc[8] = {0.f,0.f,0.f,0.f,0.f,0.f,0.f,0.f};
#pragma unroll 2
            for (int b = 0; b < 16; ++b) {
                const float w0 = Wl[(4 * b + 0) * F2 + c];
                const float w1 = Wl[(4 * b + 1) * F2 + c];
                const float w2 = Wl[(4 * b + 2) * F2 + c];
                const float w3 = Wl[(4 * b + 3) * F2 + c];
#pragma unroll
                for (int i = 0; i < 8; ++i) {
                    float4 xv = ((const float4*)xs)[(rq * 8 + i) * 16 + b];
                    acc[i] = fmaf(xv.w, w3, fmaf(xv.z, w2, fmaf(xv.y, w1, fmaf(xv.x, w0, acc[i]))));
                }
            }
#pragma unroll
            for (int i = 0; i < 8; ++i) {
                int rg = tile * 32 + rq * 8 + i;
                if (rg < hi) h[(long long)rg * H2S + c] = __float2half(acc[i] * invs[rg]);
            }
        }
        __syncthreads();
    }
}

// gather64 role (ELL): g[w,:64](fp16) = relu(iv_w*(sum hs[s] + hs[w])), nodes [lo,hi)
__device__ __forceinline__ void gather64_body(const int* __restrict__ cnt,
                                              const int* __restrict__ ell,
                                              const float* __restrict__ invs,
                                              const __half* __restrict__ h,
                                              __half* __restrict__ g,
                                              int lo, int hi, int relbid, int tid) {
    const int w = lo + relbid * 4 + (tid >> 6);
    const int lane = tid & 63;
    if (w >= hi) return;
    const int deg = min(cnt[w], ELLW);
    const int* row = ell + (long long)w * ELLW;
    float acc0 = 0.f, acc1 = 0.f, acc2 = 0.f, acc3 = 0.f;
    int k = 0;
    for (; k + 16 <= deg; k += 16) {
        int ss[16];
#pragma unroll
        for (int j = 0; j < 16; ++j) ss[j] = row[k + j];
        float vv[16];
#pragma unroll
        for (int j = 0; j < 16; ++j)
            vv[j] = __half2float(h[(long long)ss[j] * F1 + lane]);
        acc0 += ((vv[0] + vv[4]) + (vv[8]  + vv[12]));
        acc1 += ((vv[1] + vv[5]) + (vv[9]  + vv[13]));
        acc2 += ((vv[2] + vv[6]) + (vv[10] + vv[14]));
        acc3 += ((vv[3] + vv[7]) + (vv[11] + vv[15]));
    }
    for (; k + 8 <= deg; k += 8) {
        const int s0 = row[k+0], s1 = row[k+1], s2 = row[k+2], s3 = row[k+3];
        const int s4 = row[k+4], s5 = row[k+5], s6 = row[k+6], s7 = row[k+7];
        const float v0 = __half2float(h[(long long)s0 * F1 + lane]);
        const float v1 = __half2float(h[(long long)s1 * F1 + lane]);
        const float v2 = __half2float(h[(long long)s2 * F1 + lane]);
        const float v3 = __half2float(h[(long long)s3 * F1 + lane]);
        const float v4 = __half2float(h[(long long)s4 * F1 + lane]);
        const float v5 = __half2float(h[(long long)s5 * F1 + lane]);
        const float v6 = __half2float(h[(long long)s6 * F1 + lane]);
        const float v7 = __half2float(h[(long long)s7 * F1 + lane]);
        acc0 += v0 + v4; acc1 += v1 + v5; acc2 += v2 + v6; acc3 += v3 + v7;
    }
    for (; k + 2 <= deg; k += 2) {
        const int s0 = row[k], s1 = row[k+1];
        acc0 += __half2float(h[(long long)s0 * F1 + lane]);
        acc1 += __half2float(h[(long long)s1 * F1 + lane]);
    }
    if (k < deg) {
        acc0 += __half2float(h[(long long)row[k] * F1 + lane]);
    }
    const float iv = invs[w];
    const float self = __half2float(h[(long long)w * F1 + lane]);
    g[(long long)w * F1 + lane] =
        __float2half(fmaxf(iv * (((acc0 + acc1) + (acc2 + acc3)) + self), 0.f));
}

// ================= kernels built from bodies =================

// standalone gather64 over node range
__global__ __launch_bounds__(256) void k_gather64(const int* __restrict__ cnt,
                                                  const int* __restrict__ ell,
                                                  const float* __restrict__ invs,
                                                  const __half* __restrict__ h,
                                                  __half* __restrict__ g,
                                                  int lo, int hi) {
    gather64_body(cnt, ell, invs, h, g, lo, hi, blockIdx.x, threadIdx.x);
}

// pipeline stage: [0,nGm) gemm2 rows [gmlo,gmhi) | rest gather64 [g64lo,g64hi)
__global__ __launch_bounds__(256, 8) void k_stage(const __half* __restrict__ g1,
                                                  const float* __restrict__ W2,
                                                  const float* __restrict__ invs,
                                                  __half* __restrict__ h2,
                                                  const int* __restrict__ cnt,
                                                  const int* __restrict__ ell,
                                                  const __half* __restrict__ h1,
                                                  __half* __restrict__ g1out,
                                                  int n,
                                                  int nGm, int gmlo, int gmhi,
                                                  int g64lo, int g64hi) {
    const int bid = blockIdx.x;
    const int tid = threadIdx.x;
    if (bid < nGm) {
        gemm2_body(g1, W2, invs, h2, n, gmlo, gmhi, bid, nGm, tid);
    } else {
        gather64_body(cnt, ell, invs, h1, g1out, g64lo, g64hi, bid - nGm, tid);
    }
}

// standalone gemm2 over row range
__global__ __launch_bounds__(256) void k_gemm2(const __half* __restrict__ g,
                                               const float* __restrict__ W,
                                               const float* __restrict__ invs,
                                               __half* __restrict__ h,
                                               int n, int lo, int hi) {
    gemm2_body(g, W, invs, h, n, lo, hi, blockIdx.x, gridDim.x, threadIdx.x);
}

// ---------------- gather L2 (F=40, ELL), h2 stride H2S, writes fp32 out ----------------
__global__ __launch_bounds__(256) void k_gather40(const int* __restrict__ cnt,
                                                  const int* __restrict__ ell,
                                                  const float* __restrict__ invs,
                                                  const __half* __restrict__ h,
                                                  float* __restrict__ g, int n) {
    const int w = (blockIdx.x * blockDim.x + threadIdx.x) >> 6;
    const int lane = threadIdx.x & 63;
    if (w >= n) return;
    const int deg = min(cnt[w], ELLW);
    const int* row = ell + (long long)w * ELLW;
    float acc0 = 0.f, acc1 = 0.f, acc2 = 0.f, acc3 = 0.f;
    int k = 0;
    if (lane < F2) {
        for (; k + 16 <= deg; k += 16) {
            int ss[16];
#pragma unroll
            for (int j = 0; j < 16; ++j) ss[j] = row[k + j];
            float vv[16];
#pragma unroll
            for (int j = 0; j < 16; ++j)
                vv[j] = __half2float(h[(long long)ss[j] * H2S + lane]);
            acc0 += ((vv[0] + vv[4]) + (vv[8]  + vv[12]));
            acc1 += ((vv[1] + vv[5]) + (vv[9]  + vv[13]));
            acc2 += ((vv[2] + vv[6]) + (vv[10] + vv[14]));
            acc3 += ((vv[3] + vv[7]) + (vv[11] + vv[15]));
        }
        for (; k + 8 <= deg; k += 8) {
            const int s0 = row[k+0], s1 = row[k+1], s2 = row[k+2], s3 = row[k+3];
            const int s4 = row[k+4], s5 = row[k+5], s6 = row[k+6], s7 = row[k+7];
            const float v0 = __half2float(h[(long long)s0 * H2S + lane]);
            const float v1 = __half2float(h[(long long)s1 * H2S + lane]);
            const float v2 = __half2float(h[(long long)s2 * H2S + lane]);
            const float v3 = __half2float(h[(long long)s3 * H2S + lane]);
            const float v4 = __half2float(h[(long long)s4 * H2S + lane]);
            const float v5 = __half2float(h[(long long)s5 * H2S + lane]);
            const float v6 = __half2float(h[(long long)s6 * H2S + lane]);
            const float v7 = __half2float(h[(long long)s7 * H2S + lane]);
            acc0 += v0 + v4; acc1 += v1 + v5; acc2 += v2 + v6; acc3 += v3 + v7;
        }
        for (; k + 2 <= deg; k += 2) {
            const int s0 = row[k], s1 = row[k+1];
            acc0 += __half2float(h[(long long)s0 * H2S + lane]);
            acc1 += __half2float(h[(long long)s1 * H2S + lane]);
        }
        if (k < deg) {
            acc0 += __half2float(h[(long long)row[k] * H2S + lane]);
        }
        const float iv = invs[w];
        const float self = __half2float(h[(long long)w * H2S + lane]);
        g[(long long)w * F2 + lane] = fmaxf(iv * (((acc0 + acc1) + (acc2 + acc3)) + self), 0.f);
    }
}

extern "C" void kernel_launch(void* const* d_in, const int* in_sizes, int n_in,
                              void* d_out, int out_size, void* d_ws, size_t ws_size,
                              hipStream_t stream) {
    const float* x  = (const float*)d_in[0];
    const int*   ei = (const int*)d_in[1];
    const float* W1 = (const float*)d_in[2];
    const float* W2 = (const float*)d_in[3];
    float* out = (float*)d_out;
    const int n = in_sizes[0] / F0;     // 100000
    const int E = in_sizes[1] / 2;      // 1600000

    // ws layout (~64.8MB): cnt[np] | invs[np] | ell[n*64] | h1h[n*64 half]
    //                      | g1h[n*64 half] | h2h[n*H2S half]
    // h2h SEPARATE from h1h (R12 lesson); h2 rows padded to 128B (R16).
    const size_t np = ((size_t)n + 65) & ~(size_t)63;
    char* wsb = (char*)d_ws;
    int*    cnt  = (int*)wsb;
    float*  invs = (float*)(cnt + np);
    int*    ell  = (int*)(invs + np);                    // n*64 ints
    __half* h1h  = (__half*)(ell + (size_t)n * ELLW);    // n*64 halves
    __half* g1h  = h1h + (size_t)n * F1;                 // n*64 halves
    __half* h2h  = g1h + (size_t)n * F1;                 // n*H2S halves

    const int nh = ((n / 2 + 31) / 32) * 32;        // 50016: chunk split, %32==0
    const int gN = (n + 255) / 256;                 // 391
    const int nA = (nh + 3) / 4;                    // gather64-A blocks
    const int nB = (n - nh + 3) / 4;                // gather64-B blocks
    const int gW = (int)(((long long)n * 64 + 255) / 256);  // gather40 full

    // L1: zero counters
    hipLaunchKernelGGL(k_zero, dim3(gN), dim3(256), 0, stream, cnt, n);
    // L2: gemm1 || rank+ELL-fill
    hipLaunchKernelGGL(k_gemmrank, dim3(GEMM_BLKS), dim3(256), 0, stream,
                       x, W1, h1h, ei, cnt, ell, n, E);
    // L3: invs = rsqrt(cnt+1) || scale h1h rows by rsqrt(cnt[r]+1)
    hipLaunchKernelGGL(k_rsqrt_scale, dim3(gN + 2048), dim3(256), 0, stream,
                       cnt, invs, h1h, n, gN);
    // L4: gather64 [0,nh)
    hipLaunchKernelGGL(k_gather64, dim3(nA), dim3(256), 0, stream,
                       cnt, ell, invs, h1h, g1h, 0, nh);
    // L5: gemm2 rows [0,nh) || gather64 [nh,n)
    hipLaunchKernelGGL(k_stage, dim3(STG_GM + nB), dim3(256), 0, stream,
                       g1h, W2, invs, h2h, cnt, ell, h1h, g1h,
                       n, STG_GM, 0, nh, nh, n);
    // L6: gemm2 rows [nh,n)
    hipLaunchKernelGGL(k_gemm2, dim3(GEMM_BLKS), dim3(256), 0, stream,
                       g1h, W2, invs, h2h, n, nh, n);
    // L7: gather40 full
    hipLaunchKernelGGL(k_gather40, dim3(gW), dim3(256), 0, stream,
                       cnt, ell, invs, h2h, out, n);
}